// Round 1
// baseline (145.907 us; speedup 1.0000x reference)
//
#include <hip/hip_runtime.h>

#define HH 256
#define WW 512
#define NCIN 16
#define NCOUT 32
#define NB 4

// Pre-pass: x (B, Cin, H, W) -> xt (B, H, W, Cin) so one bilinear corner's 16
// channels are a contiguous 64B run (4 x float4).
__global__ __launch_bounds__(256) void transpose_x_kernel(const float* __restrict__ x,
                                                          float* __restrict__ xt) {
    const int t = blockIdx.x * 256 + threadIdx.x;   // 0 .. B*H*W-1
    const int c = t & (WW - 1);
    const int r = (t >> 9) & (HH - 1);
    const int b = t >> 17;
    const float* xp = x + ((size_t)(b * NCIN) * HH + r) * WW + c;  // coalesced per ci
    float v[NCIN];
#pragma unroll
    for (int ci = 0; ci < NCIN; ++ci) v[ci] = xp[(size_t)ci * (HH * WW)];
    float4* op = reinterpret_cast<float4*>(xt) + (size_t)t * 4;
#pragma unroll
    for (int q = 0; q < 4; ++q)
        op[q] = make_float4(v[q * 4 + 0], v[q * 4 + 1], v[q * 4 + 2], v[q * 4 + 3]);
}

// Fused grid_sample + stride-3 3x3 conv. One thread per output pixel (b,r,c),
// computing all 32 Cout. Weights staged in LDS as [cik][co] so the inner loop
// is broadcast ds_read_b128 + 32 FMAs.
template <bool XT>
__global__ __launch_bounds__(256) void sphere_conv_kernel(const float* __restrict__ x,
                                                          const float* __restrict__ xt,
                                                          const float* __restrict__ weight,
                                                          const float* __restrict__ bias,
                                                          const float* __restrict__ grid,
                                                          float* __restrict__ out) {
    __shared__ float wlds[NCIN * 9 * NCOUT];   // 18 KiB, [ci*9+k][co]
    const int tid = threadIdx.x;
    for (int e = tid; e < NCIN * 9 * NCOUT; e += 256) {
        const int co  = e & (NCOUT - 1);
        const int cik = e >> 5;                 // NCOUT == 32
        wlds[e] = weight[co * (NCIN * 9) + cik];
    }
    __syncthreads();

    const int p = blockIdx.x * 256 + tid;       // b*H*W + r*W + c
    const int c = p & (WW - 1);
    const int r = (p >> 9) & (HH - 1);
    const int b = p >> 17;

    float acc[NCOUT];
#pragma unroll
    for (int o = 0; o < NCOUT; ++o) acc[o] = 0.0f;

    const float2* g2 = reinterpret_cast<const float2*>(grid);

#pragma unroll 1
    for (int k = 0; k < 9; ++k) {
        const int kr = k / 3, kc = k - kr * 3;
        const float2 g = g2[(r * 3 + kr) * (WW * 3) + (c * 3 + kc)];
        // Match reference expression order exactly: ((g+1)*0.5)*(W-1)
        const float ix = ((g.x + 1.0f) * 0.5f) * (float)(WW - 1);
        const float iy = ((g.y + 1.0f) * 0.5f) * (float)(HH - 1);
        const float x0f = floorf(ix), y0f = floorf(iy);
        const float fx = ix - x0f, fy = iy - y0f;
        const int x0 = (int)x0f, y0 = (int)y0f;
        const int x1 = x0 + 1, y1 = y0 + 1;
        float wx0 = 1.0f - fx, wx1 = fx, wy0 = 1.0f - fy, wy1 = fy;
        if (x0 < 0 || x0 > WW - 1) wx0 = 0.0f;
        if (x1 < 0 || x1 > WW - 1) wx1 = 0.0f;
        if (y0 < 0 || y0 > HH - 1) wy0 = 0.0f;
        if (y1 < 0 || y1 > HH - 1) wy1 = 0.0f;
        const int cx0 = min(max(x0, 0), WW - 1), cx1 = min(max(x1, 0), WW - 1);
        const int cy0 = min(max(y0, 0), HH - 1), cy1 = min(max(y1, 0), HH - 1);
        const float w00 = wx0 * wy0, w01 = wx1 * wy0, w10 = wx0 * wy1, w11 = wx1 * wy1;

        if (XT) {
            const float4* xt4 = reinterpret_cast<const float4*>(xt);
            const float4* p00 = xt4 + ((b * HH + cy0) * WW + cx0) * 4;
            const float4* p01 = xt4 + ((b * HH + cy0) * WW + cx1) * 4;
            const float4* p10 = xt4 + ((b * HH + cy1) * WW + cx0) * 4;
            const float4* p11 = xt4 + ((b * HH + cy1) * WW + cx1) * 4;
#pragma unroll
            for (int q = 0; q < 4; ++q) {
                const float4 a00 = p00[q], a01 = p01[q], a10 = p10[q], a11 = p11[q];
                float sv[4];
                sv[0] = w00 * a00.x + w01 * a01.x + w10 * a10.x + w11 * a11.x;
                sv[1] = w00 * a00.y + w01 * a01.y + w10 * a10.y + w11 * a11.y;
                sv[2] = w00 * a00.z + w01 * a01.z + w10 * a10.z + w11 * a11.z;
                sv[3] = w00 * a00.w + w01 * a01.w + w10 * a10.w + w11 * a11.w;
#pragma unroll
                for (int j = 0; j < 4; ++j) {
                    const float s = sv[j];
                    const float4* wl =
                        reinterpret_cast<const float4*>(&wlds[((q * 4 + j) * 9 + k) * NCOUT]);
#pragma unroll
                    for (int o = 0; o < 8; ++o) {
                        const float4 wv = wl[o];
                        acc[o * 4 + 0] += wv.x * s;
                        acc[o * 4 + 1] += wv.y * s;
                        acc[o * 4 + 2] += wv.z * s;
                        acc[o * 4 + 3] += wv.w * s;
                    }
                }
            }
        } else {
#pragma unroll 1
            for (int ci = 0; ci < NCIN; ++ci) {
                const float* xb = x + (size_t)((b * NCIN + ci) * HH) * WW;
                const float a00 = xb[cy0 * WW + cx0];
                const float a01 = xb[cy0 * WW + cx1];
                const float a10 = xb[cy1 * WW + cx0];
                const float a11 = xb[cy1 * WW + cx1];
                const float s = w00 * a00 + w01 * a01 + w10 * a10 + w11 * a11;
                const float4* wl = reinterpret_cast<const float4*>(&wlds[(ci * 9 + k) * NCOUT]);
#pragma unroll
                for (int o = 0; o < 8; ++o) {
                    const float4 wv = wl[o];
                    acc[o * 4 + 0] += wv.x * s;
                    acc[o * 4 + 1] += wv.y * s;
                    acc[o * 4 + 2] += wv.z * s;
                    acc[o * 4 + 3] += wv.w * s;
                }
            }
        }
    }

    const int obase = ((b * NCOUT) * HH + r) * WW + c;
#pragma unroll
    for (int o = 0; o < NCOUT; ++o) {
        out[obase + o * (HH * WW)] = acc[o] + bias[o];
    }
}

extern "C" void kernel_launch(void* const* d_in, const int* in_sizes, int n_in,
                              void* d_out, int out_size, void* d_ws, size_t ws_size,
                              hipStream_t stream) {
    const float* x    = (const float*)d_in[0];
    const float* w    = (const float*)d_in[1];
    const float* bias = (const float*)d_in[2];
    const float* grid = (const float*)d_in[3];
    float* out = (float*)d_out;

    const size_t xt_bytes = (size_t)NB * HH * WW * NCIN * sizeof(float);  // 32 MiB
    const int nblocks = (NB * HH * WW) / 256;  // 2048

    if (ws_size >= xt_bytes) {
        float* xt = (float*)d_ws;
        transpose_x_kernel<<<nblocks, 256, 0, stream>>>(x, xt);
        sphere_conv_kernel<true><<<nblocks, 256, 0, stream>>>(x, xt, w, bias, grid, out);
    } else {
        sphere_conv_kernel<false><<<nblocks, 256, 0, stream>>>(x, nullptr, w, bias, grid, out);
    }
}